// Round 1
// baseline (1222.197 us; speedup 1.0000x reference)
//
#include <hip/hip_runtime.h>

#define B_ 128
#define T_ 2048
#define N_ 64
#define L_ 256
#define NEGV (-1e30f)

// One block per batch. Wave 0: fcc scan (exp-space, renormalized each step).
// Wave 1: fac scan (log-space, 4 chain cells per lane, shuffle shift).
// 8-deep register prefetch rings hide HBM latency on the sequential scans.
__global__ __launch_bounds__(128) void asg_loss_kernel(
    const float* __restrict__ x,      // (B,T,N)
    const int*   __restrict__ target, // (B,L)
    const int*   __restrict__ tsize,  // (B,)
    const float* __restrict__ trans,  // (N,N)
    float* __restrict__ out)          // (B,)
{
    __shared__ __align__(16) float sa[N_];   // fcc alpha broadcast buffer
    __shared__ float sres[2];                // [0]=fcc, [1]=fac

    const int b    = blockIdx.x;
    const int tid  = threadIdx.x;
    const int lane = tid & 63;
    const float* __restrict__ xb = x + (size_t)b * T_ * N_;

    if (tid < 64) {
        // ------------------- FCC wave (exp-space) -------------------
        // E row for this lane: E[n][m] = exp(trans[n][m]), n = lane
        float4 Er[16];
        const float4* tr4 = (const float4*)(trans + lane * N_);
        #pragma unroll
        for (int j = 0; j < 16; ++j) {
            float4 t4 = tr4[j];
            Er[j].x = __expf(t4.x); Er[j].y = __expf(t4.y);
            Er[j].z = __expf(t4.z); Er[j].w = __expf(t4.w);
        }
        // init: alpha0 = x[:,0,:]
        float x0 = xb[lane];
        float m0 = x0;
        #pragma unroll
        for (int o = 32; o > 0; o >>= 1) m0 = fmaxf(m0, __shfl_xor(m0, o));
        float  A = __expf(x0 - m0);   // A[n] = exp(alpha[n] - C)
        double C = (double)m0;

        // prefetch ring: rows t = 1..8
        float xr[8];
        #pragma unroll
        for (int i = 0; i < 8; ++i) xr[i] = xb[(1 + i) * N_ + lane];

        for (int u = 0; u < 256; ++u) {
            #pragma unroll
            for (int i = 0; i < 8; ++i) {
                const int t = 1 + u * 8 + i;      // t = 1..2048 (2048 predicated off)
                int tn = t + 8; tn = (tn > T_ - 1) ? (T_ - 1) : tn;
                const float xt = xr[i];

                sa[lane] = A;
                __asm__ volatile("s_waitcnt lgkmcnt(0)" ::: "memory");
                const float4* sa4 = (const float4*)sa;
                float4 acc = make_float4(0.f, 0.f, 0.f, 0.f);
                #pragma unroll
                for (int j = 0; j < 16; ++j) {
                    float4 av = sa4[j];           // broadcast ds_read_b128
                    acc.x = fmaf(av.x, Er[j].x, acc.x);
                    acc.y = fmaf(av.y, Er[j].y, acc.y);
                    acc.z = fmaf(av.z, Er[j].z, acc.z);
                    acc.w = fmaf(av.w, Er[j].w, acc.w);
                }
                xr[i] = xb[tn * N_ + lane];       // prefetch t+8

                float s  = (acc.x + acc.y) + (acc.z + acc.w);
                float An = __expf(xt) * s;        // exp(alpha_new - C)
                float r  = __shfl(An, 0);         // renorm scalar (never 0/inf)
                float Av = An * __builtin_amdgcn_rcpf(r);
                if (t < T_) { A = Av; C += (double)__logf(r); }
                __asm__ volatile("" ::: "memory");
            }
        }
        // fcc = C + ln(sum_n A[n])
        float ssum = A;
        #pragma unroll
        for (int o = 32; o > 0; o >>= 1) ssum += __shfl_xor(ssum, o);
        if (lane == 0) sres[0] = (float)(C + (double)__logf(ssum));
    } else {
        // ------------------- FAC wave (log-space) -------------------
        // chain cell l = j*64 + lane, j = 0..3
        int   tg[4]; float ts[4], tm[4], a[4];
        #pragma unroll
        for (int j = 0; j < 4; ++j) {
            const int l = j * 64 + lane;
            const int tv = target[b * L_ + l];
            tg[j] = tv;
            ts[j] = trans[tv * N_ + tv];                       // trans_self
            const int tp = (l > 0) ? target[b * L_ + l - 1] : 0;
            tm[j] = (l > 0) ? trans[tv * N_ + tp] : 0.f;       // trans_move
            a[j]  = (l == 0) ? xb[tv] : NEGV;                  // alpha0
        }
        // emit prefetch ring: rows t = 1..8 (gathers)
        float er[8][4];
        #pragma unroll
        for (int i = 0; i < 8; ++i)
            #pragma unroll
            for (int j = 0; j < 4; ++j)
                er[i][j] = xb[(1 + i) * N_ + tg[j]];

        for (int u = 0; u < 256; ++u) {
            #pragma unroll
            for (int i = 0; i < 8; ++i) {
                const int t = 1 + u * 8 + i;
                int tn = t + 8; tn = (tn > T_ - 1) ? (T_ - 1) : tn;
                // snapshot lane-63 carries of OLD alpha
                float carry[4];
                #pragma unroll
                for (int j = 0; j < 4; ++j) carry[j] = __shfl(a[j], 63);
                #pragma unroll
                for (int j = 0; j < 4; ++j) {
                    float up = __shfl_up(a[j], 1);             // old a[l-1]
                    if (lane == 0) up = (j == 0) ? NEGV : carry[j - 1];
                    const float stay = a[j] + ts[j];
                    const float mv   = up   + tm[j];
                    const float mx   = fmaxf(stay, mv);
                    const float d    = fabsf(stay - mv);
                    const float lse  = mx + __logf(1.0f + __expf(-d));
                    const float an   = er[i][j] + lse;
                    a[j] = (t < T_) ? an : a[j];
                    er[i][j] = xb[tn * N_ + tg[j]];            // prefetch t+8
                }
            }
        }
        const int lt = tsize[b] - 1;
        #pragma unroll
        for (int j = 0; j < 4; ++j)
            if (j * 64 + lane == lt) sres[1] = a[j];
    }

    __syncthreads();
    if (tid == 0) out[b] = sres[0] - sres[1];
}

extern "C" void kernel_launch(void* const* d_in, const int* in_sizes, int n_in,
                              void* d_out, int out_size, void* d_ws, size_t ws_size,
                              hipStream_t stream) {
    const float* xin    = (const float*)d_in[0];  // (B,T,N) fp32
    const int*   target = (const int*)  d_in[1];  // (B,L) int32
    const int*   tsz    = (const int*)  d_in[2];  // (B,) int32
    const float* trans  = (const float*)d_in[3];  // (N,N) fp32
    float* out = (float*)d_out;                   // (B,) fp32

    asg_loss_kernel<<<dim3(B_), dim3(128), 0, stream>>>(xin, target, tsz, trans, out);
}

// Round 2
// 582.535 us; speedup vs baseline: 2.0981x; 2.0981x over previous
//
#include <hip/hip_runtime.h>

#define B_ 128
#define T_ 2048
#define N_ 64
#define L_ 256
#define NEGV (-1e30f)
#define PITCH 72   // bf16 elements per LDS n-row (64 + 8 pad -> 2-way-conflict-free)

typedef short  s16x4 __attribute__((ext_vector_type(4)));
typedef short  s16x8 __attribute__((ext_vector_type(8)));
typedef float  f32x4 __attribute__((ext_vector_type(4)));

__device__ __forceinline__ short f2bf_rne(float f) {
    unsigned u = __float_as_uint(f);
    unsigned r = (u + 0x7FFFu + ((u >> 16) & 1u)) >> 16;
    return (short)r;
}
__device__ __forceinline__ short f2bf_trunc(float f) {
    return (short)(__float_as_uint(f) >> 16);
}
__device__ __forceinline__ float bf2f(unsigned short u) {
    return __uint_as_float(((unsigned)u) << 16);
}
__device__ __forceinline__ float lse2(float p, float q) {
    float mx = fmaxf(p, q);
    float d  = fabsf(p - q);
    return mx + __logf(1.f + __expf(-d));
}

// Kernel 1: waves 0..127 = fac chains (dispatched first); waves 128.. = fcc chunk
// transfer-matrix builders (one (b,chunk) per wave, 64 MFMA-steps each).
__global__ __launch_bounds__(256, 2) void asg_k1(
    const float* __restrict__ x,       // (B,T,N)
    const int*   __restrict__ target,  // (B,L)
    const int*   __restrict__ tsize,   // (B,)
    const float* __restrict__ trans,   // (N,N)
    float* __restrict__ ws_c,          // (B,32) chunk log-scales
    unsigned short* __restrict__ ws_R, // (B,32,64,64) bf16 chunk matrices, [n][j]
    float* __restrict__ ws_fac)        // (B,)
{
    __shared__ short lds[4][N_ * PITCH];
    const int wid  = threadIdx.x >> 6;
    const int lane = threadIdx.x & 63;
    const int W    = blockIdx.x * 4 + wid;

    if (W < B_) {
        // ---------------- FAC: log-space chain, cells l = 4*lane + j ----------------
        const int b = W;
        const float* __restrict__ xb = x + (size_t)b * T_ * N_;
        int tg[4]; float tself[4], tmove[4], a[4];
        #pragma unroll
        for (int j = 0; j < 4; ++j) {
            const int l  = lane * 4 + j;
            const int tv = target[b * L_ + l];
            tg[j]    = tv;
            tself[j] = trans[tv * N_ + tv];
            const int tp = (l > 0) ? target[b * L_ + l - 1] : 0;
            tmove[j] = (l > 0) ? trans[tv * N_ + tp] : 0.f;
            a[j]     = (l == 0) ? xb[tv] : NEGV;
        }
        float er[16][4];                       // 16-step emission prefetch ring
        #pragma unroll
        for (int i = 0; i < 16; ++i)
            #pragma unroll
            for (int j = 0; j < 4; ++j)
                er[i][j] = xb[(1 + i) * N_ + tg[j]];

        for (int u = 0; u < 128; ++u) {
            #pragma unroll
            for (int i = 0; i < 16; ++i) {
                const int t = u * 16 + i + 1;          // 1..2048 (2048 predicated)
                float up0 = __shfl_up(a[3], 1);        // old a[l-1] for j==0
                if (lane == 0) up0 = NEGV;
                const float n0 = lse2(a[0] + tself[0], up0  + tmove[0]) + er[i][0];
                const float n1 = lse2(a[1] + tself[1], a[0] + tmove[1]) + er[i][1];
                const float n2 = lse2(a[2] + tself[2], a[1] + tmove[2]) + er[i][2];
                const float n3 = lse2(a[3] + tself[3], a[2] + tmove[3]) + er[i][3];
                const bool ok = (t < T_);
                a[0] = ok ? n0 : a[0]; a[1] = ok ? n1 : a[1];
                a[2] = ok ? n2 : a[2]; a[3] = ok ? n3 : a[3];
                int tn = t + 16; if (tn > T_ - 1) tn = T_ - 1;
                er[i][0] = xb[tn * N_ + tg[0]];
                er[i][1] = xb[tn * N_ + tg[1]];
                er[i][2] = xb[tn * N_ + tg[2]];
                er[i][3] = xb[tn * N_ + tg[3]];
            }
        }
        const int lt = tsize[b] - 1;
        if (lane == (lt >> 2)) {
            float sel = a[0];
            if ((lt & 3) == 1) sel = a[1];
            if ((lt & 3) == 2) sel = a[2];
            if ((lt & 3) == 3) sel = a[3];
            ws_fac[b] = sel;
        }
    } else {
        // ---------------- FCC chunk: P = prod_{s} D_t*Ehat over 64 steps ----------
        const int task = W - B_;
        const int b = task >> 5, k = task & 31;
        const int c = lane & 15, g = lane >> 4;
        const float* __restrict__ xb = x + (size_t)b * T_ * N_;
        const int t0 = k * 64;
        short* __restrict__ myl = lds[wid];

        // A = Ehat (const): A[m=c+16mt][kk=32kt+8g+jj], plus row-sums for LS
        s16x8 Afrag[4][2];
        float rs[4] = {0.f, 0.f, 0.f, 0.f};
        #pragma unroll
        for (int mt = 0; mt < 4; ++mt)
            #pragma unroll
            for (int kt = 0; kt < 2; ++kt) {
                s16x8 af;
                #pragma unroll
                for (int jj = 0; jj < 8; ++jj) {
                    float v = __expf(trans[(c + 16 * mt) * N_ + 32 * kt + 8 * g + jj]);
                    af[jj] = f2bf_rne(v);
                    rs[mt] += v;
                }
                Afrag[mt][kt] = af;
            }
        // LS = log(max_row rowsum): reduce partial sums over g-groups, then max
        #pragma unroll
        for (int mt = 0; mt < 4; ++mt) {
            rs[mt] += __shfl_xor(rs[mt], 16);
            rs[mt] += __shfl_xor(rs[mt], 32);
        }
        float rmax = fmaxf(fmaxf(rs[0], rs[1]), fmaxf(rs[2], rs[3]));
        #pragma unroll
        for (int o = 8; o > 0; o >>= 1) rmax = fmaxf(rmax, __shfl_xor(rmax, o));
        const float LS = __logf(rmax);

        // B = identity: B[kk=32kt+8g+jj][n=c+16nt]
        s16x8 Bfrag[2][4];
        #pragma unroll
        for (int kt = 0; kt < 2; ++kt)
            #pragma unroll
            for (int nt = 0; nt < 4; ++nt) {
                s16x8 bf;
                #pragma unroll
                for (int jj = 0; jj < 8; ++jj)
                    bf[jj] = (32 * kt + 8 * g + jj == c + 16 * nt) ? (short)0x3F80 : (short)0;
                Bfrag[kt][nt] = bf;
            }

        // x prefetch ring (2 steps deep), rows t0+1, t0+2
        float4 xr[2][4];
        #pragma unroll
        for (int p = 0; p < 2; ++p)
            #pragma unroll
            for (int tr = 0; tr < 4; ++tr)
                xr[p][tr] = *(const float4*)(xb + (size_t)(t0 + 1 + p) * N_ + 16 * tr + 4 * g);

        float c_acc = 0.f;
        #pragma unroll 2
        for (int s = 0; s < 64; ++s) {
            const int t = t0 + 1 + s;
            f32x4 Cacc[4][4];
            #pragma unroll
            for (int mt = 0; mt < 4; ++mt)
                #pragma unroll
                for (int nt = 0; nt < 4; ++nt) {
                    f32x4 z = {0.f, 0.f, 0.f, 0.f};
                    z = __builtin_amdgcn_mfma_f32_16x16x32_bf16(Afrag[mt][0], Bfrag[0][nt], z, 0, 0, 0);
                    Cacc[mt][nt] = __builtin_amdgcn_mfma_f32_16x16x32_bf16(Afrag[mt][1], Bfrag[1][nt], z, 0, 0, 0);
                }
            float4 xv[4];
            #pragma unroll
            for (int tr = 0; tr < 4; ++tr) xv[tr] = xr[s & 1][tr];
            int tpre = t + 2; if (tpre > T_ - 1) tpre = T_ - 1;
            #pragma unroll
            for (int tr = 0; tr < 4; ++tr)
                xr[s & 1][tr] = *(const float4*)(xb + (size_t)tpre * N_ + 16 * tr + 4 * g);

            const float gt = __uint_as_float(__builtin_amdgcn_readfirstlane(__float_as_uint(xv[0].x))) + LS;
            if (t < T_) {
                c_acc += gt;
                float ev[4][4];
                #pragma unroll
                for (int tr = 0; tr < 4; ++tr) {
                    ev[tr][0] = __expf(xv[tr].x - gt);
                    ev[tr][1] = __expf(xv[tr].y - gt);
                    ev[tr][2] = __expf(xv[tr].z - gt);
                    ev[tr][3] = __expf(xv[tr].w - gt);
                }
                // scale rows, pack bf16, write LDS col-major [n][j] (b64 per tile)
                #pragma unroll
                for (int mt = 0; mt < 4; ++mt)
                    #pragma unroll
                    for (int nt = 0; nt < 4; ++nt) {
                        s16x4 pk;
                        pk[0] = f2bf_trunc(Cacc[mt][nt][0] * ev[mt][0]);
                        pk[1] = f2bf_trunc(Cacc[mt][nt][1] * ev[mt][1]);
                        pk[2] = f2bf_trunc(Cacc[mt][nt][2] * ev[mt][2]);
                        pk[3] = f2bf_trunc(Cacc[mt][nt][3] * ev[mt][3]);
                        *(s16x4*)&myl[(16 * nt + c) * PITCH + 16 * mt + 4 * g] = pk;
                    }
                // read back as next-step B-frags (b128)
                #pragma unroll
                for (int kt = 0; kt < 2; ++kt)
                    #pragma unroll
                    for (int nt = 0; nt < 4; ++nt)
                        Bfrag[kt][nt] = *(const s16x8*)&myl[(16 * nt + c) * PITCH + 32 * kt + 8 * g];
            }
        }
        // store chunk matrix R[n][j] = P[j][n] and scale
        unsigned short* dst = ws_R + (size_t)(b * 32 + k) * 4096;
        #pragma unroll
        for (int i = 0; i < 8; ++i)
            *(s16x8*)&dst[lane * 64 + i * 8] = *(const s16x8*)&myl[lane * PITCH + i * 8];
        if (lane == 0) ws_c[b * 32 + k] = c_acc;
    }
}

// Kernel 2: per-batch sequential combine over 32 chunk matrices + final output.
__global__ __launch_bounds__(64) void asg_k2(
    const float* __restrict__ x,
    const float* __restrict__ ws_c,
    const unsigned short* __restrict__ ws_R,
    const float* __restrict__ ws_fac,
    float* __restrict__ out)
{
    __shared__ float sa[N_];
    const int b = blockIdx.x, lane = threadIdx.x;
    float a0 = x[(size_t)b * T_ * N_ + lane];
    float m0 = a0;
    #pragma unroll
    for (int o = 32; o > 0; o >>= 1) m0 = fmaxf(m0, __shfl_xor(m0, o));
    float  a  = __expf(a0 - m0);
    double Cd = (double)m0;

    for (int kk = 0; kk < 32; ++kk) {
        sa[lane] = a;
        const unsigned short* R = ws_R + (size_t)(b * 32 + kk) * 4096;
        float acc0 = 0.f, acc1 = 0.f;
        #pragma unroll 8
        for (int n = 0; n < 64; n += 2) {
            acc0 = fmaf(bf2f(R[n * 64 + lane]),       sa[n],     acc0);
            acc1 = fmaf(bf2f(R[(n + 1) * 64 + lane]), sa[n + 1], acc1);
        }
        float acc = acc0 + acc1;
        float rm = acc;
        #pragma unroll
        for (int o = 32; o > 0; o >>= 1) rm = fmaxf(rm, __shfl_xor(rm, o));
        a = acc / rm;
        Cd += (double)(__logf(rm) + ws_c[b * 32 + kk]);
    }
    float ssum = a;
    #pragma unroll
    for (int o = 32; o > 0; o >>= 1) ssum += __shfl_xor(ssum, o);
    if (lane == 0) {
        float fcc = (float)(Cd + (double)__logf(ssum));
        out[b] = fcc - ws_fac[b];
    }
}

extern "C" void kernel_launch(void* const* d_in, const int* in_sizes, int n_in,
                              void* d_out, int out_size, void* d_ws, size_t ws_size,
                              hipStream_t stream) {
    (void)in_sizes; (void)n_in; (void)out_size; (void)ws_size;
    const float* xin    = (const float*)d_in[0];
    const int*   target = (const int*)  d_in[1];
    const int*   tsz    = (const int*)  d_in[2];
    const float* trans  = (const float*)d_in[3];
    float* out = (float*)d_out;

    float*          ws_c   = (float*)d_ws;                                   // 16 KB
    unsigned short* ws_R   = (unsigned short*)((char*)d_ws + 16384);         // 33.55 MB
    float*          ws_fac = (float*)((char*)d_ws + 16384 + (size_t)B_ * 32 * 4096 * 2);

    // (128 fac waves + 4096 chunk waves) / 4 waves-per-block = 1056 blocks
    asg_k1<<<dim3(1056), dim3(256), 0, stream>>>(xin, target, tsz, trans, ws_c, ws_R, ws_fac);
    asg_k2<<<dim3(B_), dim3(64), 0, stream>>>(xin, ws_c, ws_R, ws_fac, out);
}

// Round 3
// 577.087 us; speedup vs baseline: 2.1179x; 1.0094x over previous
//
#include <hip/hip_runtime.h>

#define B_ 128
#define T_ 2048
#define N_ 64
#define L_ 256
#define NEGV (-1e30f)
#define PITCH 72   // bf16 elements per LDS n-row (64 + 8 pad)

typedef short  s16x4 __attribute__((ext_vector_type(4)));
typedef short  s16x8 __attribute__((ext_vector_type(8)));
typedef float  f32x4 __attribute__((ext_vector_type(4)));

__device__ __forceinline__ short f2bf_rne(float f) {
    unsigned u = __float_as_uint(f);
    unsigned r = (u + 0x7FFFu + ((u >> 16) & 1u)) >> 16;
    return (short)r;
}
__device__ __forceinline__ short f2bf_rhu(float f) {   // round-half-up: unbiased-ish, 1 add
    return (short)((__float_as_uint(f) + 0x8000u) >> 16);
}
__device__ __forceinline__ float bf2f(unsigned short u) {
    return __uint_as_float(((unsigned)u) << 16);
}
__device__ __forceinline__ float lse2(float p, float q) {
    float mx = fmaxf(p, q);
    float d  = p - q;
    return mx + __logf(1.f + __expf(-fabsf(d)));   // -abs folds into exp input modifier
}

// Kernel 1: blocks 0..31 = fac chains (scheduled first); rest = fcc chunk builders.
__global__ __launch_bounds__(256, 2) void asg_k1(
    const float* __restrict__ x,       // (B,T,N)
    const int*   __restrict__ target,  // (B,L)
    const int*   __restrict__ tsize,   // (B,)
    const float* __restrict__ trans,   // (N,N)
    float* __restrict__ ws_c,          // (B,32) chunk log-scales
    unsigned short* __restrict__ ws_R, // (B,32,64,64) bf16 chunk matrices, [n][m]
    float* __restrict__ ws_fac)        // (B,)
{
    __shared__ short lds[4][N_ * PITCH];
    const int wid  = threadIdx.x >> 6;
    const int lane = threadIdx.x & 63;
    const int W    = blockIdx.x * 4 + wid;

    if (W < B_) {
        // ---------------- FAC: log-space chain, cells l = 4*lane + j ----------------
        const int b = W;
        const float* __restrict__ xb = x + (size_t)b * T_ * N_;
        int tg[4]; float tself[4], tmove[4], a[4];
        #pragma unroll
        for (int j = 0; j < 4; ++j) {
            const int l  = lane * 4 + j;
            const int tv = target[b * L_ + l];
            tg[j]    = tv;
            tself[j] = trans[tv * N_ + tv];
            const int tp = (l > 0) ? target[b * L_ + l - 1] : 0;
            tmove[j] = (l > 0) ? trans[tv * N_ + tp] : 0.f;
            a[j]     = (l == 0) ? xb[tv] : NEGV;
        }
        float er[16][4];                       // 16-step emission prefetch ring
        #pragma unroll
        for (int i = 0; i < 16; ++i) {
            const float* __restrict__ xr = xb + (size_t)(1 + i) * N_;
            er[i][0] = xr[tg[0]]; er[i][1] = xr[tg[1]];
            er[i][2] = xr[tg[2]]; er[i][3] = xr[tg[3]];
        }

        // one scan step consuming ring slot i; optionally refill from uniform row ptr
        #define FAC_STEP(i, xp, REFILL)                                          \
        {                                                                        \
            float up0 = __shfl_up(a[3], 1);                                      \
            if (lane == 0) up0 = NEGV;                                           \
            const float n0 = lse2(a[0] + tself[0], up0  + tmove[0]) + er[i][0];  \
            const float n1 = lse2(a[1] + tself[1], a[0] + tmove[1]) + er[i][1];  \
            const float n2 = lse2(a[2] + tself[2], a[1] + tmove[2]) + er[i][2];  \
            const float n3 = lse2(a[3] + tself[3], a[2] + tmove[3]) + er[i][3];  \
            a[0] = n0; a[1] = n1; a[2] = n2; a[3] = n3;                          \
            if (REFILL) {                                                        \
                er[i][0] = (xp)[tg[0]]; er[i][1] = (xp)[tg[1]];                  \
                er[i][2] = (xp)[tg[2]]; er[i][3] = (xp)[tg[3]];                  \
            }                                                                    \
        }

        // main: u=0..125 -> t = 16u+1 .. 16u+16, refill rows t+16 (max 2032)
        for (int u = 0; u < 126; ++u) {
            const float* __restrict__ xp = xb + (size_t)(16 * (u + 1) + 1) * N_;
            #pragma unroll
            for (int i = 0; i < 16; ++i) FAC_STEP(i, xp + i * N_, true);
        }
        // tail A: t=2017..2031, refill rows 2033..2047
        {
            const float* __restrict__ xp = xb + (size_t)2033 * N_;
            #pragma unroll
            for (int i = 0; i < 15; ++i) FAC_STEP(i, xp + i * N_, true);
        }
        // t=2032 (slot 15), then t=2033..2047 (slots 0..14), no refill
        FAC_STEP(15, xb, false);
        #pragma unroll
        for (int i = 0; i < 15; ++i) FAC_STEP(i, xb, false);
        #undef FAC_STEP

        const int lt = tsize[b] - 1;
        if (lane == (lt >> 2)) {
            float sel = a[0];
            if ((lt & 3) == 1) sel = a[1];
            if ((lt & 3) == 2) sel = a[2];
            if ((lt & 3) == 3) sel = a[3];
            ws_fac[b] = sel;
        }
    } else {
        // ---------------- FCC chunk: P = prod_s D_t*Ehat over 64 steps ------------
        const int task = W - B_;
        const int b = task >> 5, k = task & 31;
        const int c = lane & 15, g = lane >> 4;
        const float* __restrict__ xb = x + (size_t)b * T_ * N_;
        const int t0 = k * 64;
        short* __restrict__ myl = lds[wid];

        // A = Ehat (const): A[m=c+16mt][kk=32kt+8g+jj], plus row-sums for LS
        s16x8 Afrag[4][2];
        float rs[4] = {0.f, 0.f, 0.f, 0.f};
        #pragma unroll
        for (int mt = 0; mt < 4; ++mt)
            #pragma unroll
            for (int kt = 0; kt < 2; ++kt) {
                s16x8 af;
                #pragma unroll
                for (int jj = 0; jj < 8; ++jj) {
                    float v = __expf(trans[(c + 16 * mt) * N_ + 32 * kt + 8 * g + jj]);
                    af[jj] = f2bf_rne(v);
                    rs[mt] += v;
                }
                Afrag[mt][kt] = af;
            }
        #pragma unroll
        for (int mt = 0; mt < 4; ++mt) {
            rs[mt] += __shfl_xor(rs[mt], 16);
            rs[mt] += __shfl_xor(rs[mt], 32);
        }
        float rmax = fmaxf(fmaxf(rs[0], rs[1]), fmaxf(rs[2], rs[3]));
        #pragma unroll
        for (int o = 8; o > 0; o >>= 1) rmax = fmaxf(rmax, __shfl_xor(rmax, o));
        const float LS = __logf(rmax);

        // B = identity: B[kk=32kt+8g+jj][n=c+16nt]
        s16x8 Bfrag[2][4];
        #pragma unroll
        for (int kt = 0; kt < 2; ++kt)
            #pragma unroll
            for (int nt = 0; nt < 4; ++nt) {
                s16x8 bf;
                #pragma unroll
                for (int jj = 0; jj < 8; ++jj)
                    bf[jj] = (32 * kt + 8 * g + jj == c + 16 * nt) ? (short)0x3F80 : (short)0;
                Bfrag[kt][nt] = bf;
            }

        // x prefetch ring (2 deep)
        float4 xr[2][4];
        #pragma unroll
        for (int p = 0; p < 2; ++p)
            #pragma unroll
            for (int tr = 0; tr < 4; ++tr)
                xr[p][tr] = *(const float4*)(xb + (size_t)(t0 + 1 + p) * N_ + 16 * tr + 4 * g);

        float c_acc = 0.f;
        #pragma unroll 2
        for (int s = 0; s < 64; ++s) {
            const int t = t0 + 1 + s;
            f32x4 Cacc[4][4];
            #pragma unroll
            for (int mt = 0; mt < 4; ++mt)
                #pragma unroll
                for (int nt = 0; nt < 4; ++nt) {
                    f32x4 z = {0.f, 0.f, 0.f, 0.f};
                    z = __builtin_amdgcn_mfma_f32_16x16x32_bf16(Afrag[mt][0], Bfrag[0][nt], z, 0, 0, 0);
                    Cacc[mt][nt] = __builtin_amdgcn_mfma_f32_16x16x32_bf16(Afrag[mt][1], Bfrag[1][nt], z, 0, 0, 0);
                }
            float4 xv[4];
            #pragma unroll
            for (int tr = 0; tr < 4; ++tr) xv[tr] = xr[s & 1][tr];
            int tpre = t + 2; if (tpre > T_ - 1) tpre = T_ - 1;
            #pragma unroll
            for (int tr = 0; tr < 4; ++tr)
                xr[s & 1][tr] = *(const float4*)(xb + (size_t)tpre * N_ + 16 * tr + 4 * g);

            const float gt = __uint_as_float(__builtin_amdgcn_readfirstlane(__float_as_uint(xv[0].x))) + LS;
            if (t < T_) {
                c_acc += gt;
                float ev[4][4];
                #pragma unroll
                for (int tr = 0; tr < 4; ++tr) {
                    ev[tr][0] = __expf(xv[tr].x - gt);
                    ev[tr][1] = __expf(xv[tr].y - gt);
                    ev[tr][2] = __expf(xv[tr].z - gt);
                    ev[tr][3] = __expf(xv[tr].w - gt);
                }
                #pragma unroll
                for (int mt = 0; mt < 4; ++mt)
                    #pragma unroll
                    for (int nt = 0; nt < 4; ++nt) {
                        s16x4 pk;
                        pk[0] = f2bf_rhu(Cacc[mt][nt][0] * ev[mt][0]);
                        pk[1] = f2bf_rhu(Cacc[mt][nt][1] * ev[mt][1]);
                        pk[2] = f2bf_rhu(Cacc[mt][nt][2] * ev[mt][2]);
                        pk[3] = f2bf_rhu(Cacc[mt][nt][3] * ev[mt][3]);
                        *(s16x4*)&myl[(16 * nt + c) * PITCH + 16 * mt + 4 * g] = pk;
                    }
                #pragma unroll
                for (int kt = 0; kt < 2; ++kt)
                    #pragma unroll
                    for (int nt = 0; nt < 4; ++nt)
                        Bfrag[kt][nt] = *(const s16x8*)&myl[(16 * nt + c) * PITCH + 32 * kt + 8 * g];
            }
        }
        unsigned short* dst = ws_R + (size_t)(b * 32 + k) * 4096;
        #pragma unroll
        for (int i = 0; i < 8; ++i)
            *(s16x8*)&dst[lane * 64 + i * 8] = *(const s16x8*)&myl[lane * PITCH + i * 8];
        if (lane == 0) ws_c[b * 32 + k] = c_acc;
    }
}

// Kernel 2: per-batch sequential combine over 32 chunk matrices + final output.
__global__ __launch_bounds__(64) void asg_k2(
    const float* __restrict__ x,
    const float* __restrict__ ws_c,
    const unsigned short* __restrict__ ws_R,
    const float* __restrict__ ws_fac,
    float* __restrict__ out)
{
    __shared__ float sa[N_];
    const int b = blockIdx.x, lane = threadIdx.x;
    float a0 = x[(size_t)b * T_ * N_ + lane];
    float m0 = a0;
    #pragma unroll
    for (int o = 32; o > 0; o >>= 1) m0 = fmaxf(m0, __shfl_xor(m0, o));
    float  a  = __expf(a0 - m0);
    double Cd = (double)m0;

    for (int kk = 0; kk < 32; ++kk) {
        sa[lane] = a;
        const unsigned short* R = ws_R + (size_t)(b * 32 + kk) * 4096;
        float acc0 = 0.f, acc1 = 0.f;
        #pragma unroll 8
        for (int n = 0; n < 64; n += 2) {
            acc0 = fmaf(bf2f(R[n * 64 + lane]),       sa[n],     acc0);
            acc1 = fmaf(bf2f(R[(n + 1) * 64 + lane]), sa[n + 1], acc1);
        }
        float acc = acc0 + acc1;
        float rm = acc;
        #pragma unroll
        for (int o = 32; o > 0; o >>= 1) rm = fmaxf(rm, __shfl_xor(rm, o));
        a = acc / rm;
        Cd += (double)(__logf(rm) + ws_c[b * 32 + kk]);
    }
    float ssum = a;
    #pragma unroll
    for (int o = 32; o > 0; o >>= 1) ssum += __shfl_xor(ssum, o);
    if (lane == 0) {
        float fcc = (float)(Cd + (double)__logf(ssum));
        out[b] = fcc - ws_fac[b];
    }
}

extern "C" void kernel_launch(void* const* d_in, const int* in_sizes, int n_in,
                              void* d_out, int out_size, void* d_ws, size_t ws_size,
                              hipStream_t stream) {
    (void)in_sizes; (void)n_in; (void)out_size; (void)ws_size;
    const float* xin    = (const float*)d_in[0];
    const int*   target = (const int*)  d_in[1];
    const int*   tsz    = (const int*)  d_in[2];
    const float* trans  = (const float*)d_in[3];
    float* out = (float*)d_out;

    float*          ws_c   = (float*)d_ws;                                   // 16 KB
    unsigned short* ws_R   = (unsigned short*)((char*)d_ws + 16384);         // 33.55 MB
    float*          ws_fac = (float*)((char*)d_ws + 16384 + (size_t)B_ * 32 * 4096 * 2);

    asg_k1<<<dim3(1056), dim3(256), 0, stream>>>(xin, target, tsz, trans, ws_c, ws_R, ws_fac);
    asg_k2<<<dim3(B_), dim3(64), 0, stream>>>(xin, ws_c, ws_R, ws_fac, out);
}

// Round 4
// 393.777 us; speedup vs baseline: 3.1038x; 1.4655x over previous
//
#include <hip/hip_runtime.h>

#define B_ 128
#define T_ 2048
#define N_ 64
#define L_ 256
#define NEGV (-1e30f)
#define PITCH 72   // bf16 elements per LDS n-row (64 + 8 pad)
#define LOG2E 1.4426950408889634f
#define LN2   0.6931471805599453f

typedef short  s16x4 __attribute__((ext_vector_type(4)));
typedef short  s16x8 __attribute__((ext_vector_type(8)));
typedef float  f32x4 __attribute__((ext_vector_type(4)));

__device__ __forceinline__ short f2bf_rne(float f) {
    unsigned u = __float_as_uint(f);
    unsigned r = (u + 0x7FFFu + ((u >> 16) & 1u)) >> 16;
    return (short)r;
}
__device__ __forceinline__ short f2bf_rhu(float f) {
    return (short)((__float_as_uint(f) + 0x8000u) >> 16);
}
__device__ __forceinline__ float bf2f(unsigned short u) {
    return __uint_as_float(((unsigned)u) << 16);
}
__device__ __forceinline__ float bperm(int byteaddr, float v) {
    return __int_as_float(__builtin_amdgcn_ds_bpermute(byteaddr, __float_as_int(v)));
}
// logaddexp in log2 domain: raw v_exp_f32/v_log_f32, no base fixups
__device__ __forceinline__ float lse2b(float p, float q) {
    float mx = fmaxf(p, q);
    float t  = __builtin_amdgcn_exp2f(-fabsf(p - q));
    return mx + __builtin_amdgcn_logf(1.f + t);
}

// Kernel 1: blocks 0..31 = fac chains; rest = fcc chunk transfer-matrix builders.
__global__ __launch_bounds__(256, 2) void asg_k1(
    const float* __restrict__ x,       // (B,T,N)
    const int*   __restrict__ target,  // (B,L)
    const int*   __restrict__ tsize,   // (B,)
    const float* __restrict__ trans,   // (N,N)
    float* __restrict__ ws_c,          // (B,32) chunk log-scales
    unsigned short* __restrict__ ws_R, // (B,32,64,64) bf16 chunk matrices, [m][n]
    float* __restrict__ ws_fac)        // (B,)
{
    __shared__ short lds[4][N_ * PITCH];
    const int wid  = threadIdx.x >> 6;
    const int lane = threadIdx.x & 63;
    const int W    = blockIdx.x * 4 + wid;

    if (W < B_) {
        // ------- FAC: log2-space chain, cells l = 4*lane + j, bpermute gathers -------
        const int b = W;
        const float* __restrict__ xb = x + (size_t)b * T_ * N_;
        int tg4[4]; float tsl[4], tmv[4], a[4];
        #pragma unroll
        for (int j = 0; j < 4; ++j) {
            const int l  = lane * 4 + j;
            const int tv = target[b * L_ + l];
            tg4[j] = tv << 2;
            tsl[j] = trans[tv * N_ + tv] * LOG2E;
            const int tp = (l > 0) ? target[b * L_ + l - 1] : 0;
            tmv[j] = (l > 0) ? trans[tv * N_ + tp] * LOG2E : 0.f;
            a[j]   = (l == 0) ? xb[tv] * LOG2E : NEGV;
        }
        const int upaddr = ((lane == 0) ? 0 : (lane - 1)) << 2;

        // coalesced row ring: slot i holds x[t] row for t = 16u+1+i
        float xr[16];
        #pragma unroll
        for (int i = 0; i < 16; ++i) xr[i] = xb[(size_t)(1 + i) * N_ + lane];
        // gather for t=1 from slot 0
        float sc0 = xr[0] * LOG2E;
        float e0 = bperm(tg4[0], sc0), e1 = bperm(tg4[1], sc0),
              e2 = bperm(tg4[2], sc0), e3 = bperm(tg4[3], sc0);

        // step t (slot i=(t-1)&15): consume e*, gather next from slot (i+1)&15,
        // refill slot i with row t+16 (coalesced), run 4 lse2b chain cells.
        #define FAC_STEP(i, rowptr, REFILL)                                       \
        {                                                                         \
            const float ce0 = e0, ce1 = e1, ce2 = e2, ce3 = e3;                   \
            float scn = xr[((i) + 1) & 15] * LOG2E;                               \
            e0 = bperm(tg4[0], scn); e1 = bperm(tg4[1], scn);                     \
            e2 = bperm(tg4[2], scn); e3 = bperm(tg4[3], scn);                     \
            if (REFILL) xr[i] = (rowptr)[lane];                                   \
            float up0 = bperm(upaddr, a[3]);                                      \
            if (lane == 0) up0 = NEGV;                                            \
            const float n0 = lse2b(a[0] + tsl[0], up0  + tmv[0]) + ce0;           \
            const float n1 = lse2b(a[1] + tsl[1], a[0] + tmv[1]) + ce1;           \
            const float n2 = lse2b(a[2] + tsl[2], a[1] + tmv[2]) + ce2;           \
            const float n3 = lse2b(a[3] + tsl[3], a[2] + tmv[3]) + ce3;           \
            a[0] = n0; a[1] = n1; a[2] = n2; a[3] = n3;                           \
        }

        // main: u=0..126 -> t = 16u+1 .. 16u+16, refill rows 16u+17+i (clamped)
        for (int u = 0; u < 127; ++u) {
            #pragma unroll
            for (int i = 0; i < 16; ++i) {
                int ri = 16 * u + 17 + i;
                if (ri > T_ - 1) ri = T_ - 1;
                const float* rp = xb + (size_t)ri * N_;
                FAC_STEP(i, rp, true);
            }
        }
        // tail: t = 2033..2047 (slots 0..14), no refill
        #pragma unroll
        for (int i = 0; i < 15; ++i) FAC_STEP(i, xb, false);
        #undef FAC_STEP

        const int lt = tsize[b] - 1;
        if (lane == (lt >> 2)) {
            float sel = a[0];
            if ((lt & 3) == 1) sel = a[1];
            if ((lt & 3) == 2) sel = a[2];
            if ((lt & 3) == 3) sel = a[3];
            ws_fac[b] = sel * LN2;     // log2 -> ln
        }
    } else {
        // ---------------- FCC chunk: P = prod_s D_t*Ehat over 64 steps ------------
        const int task = W - B_;
        const int b = task >> 5, k = task & 31;
        const int c = lane & 15, g = lane >> 4;
        const float* __restrict__ xb = x + (size_t)b * T_ * N_;
        const int t0 = k * 64;
        short* __restrict__ myl = lds[wid];

        s16x8 Afrag[4][2];
        float rs[4] = {0.f, 0.f, 0.f, 0.f};
        #pragma unroll
        for (int mt = 0; mt < 4; ++mt)
            #pragma unroll
            for (int kt = 0; kt < 2; ++kt) {
                s16x8 af;
                #pragma unroll
                for (int jj = 0; jj < 8; ++jj) {
                    float v = __expf(trans[(c + 16 * mt) * N_ + 32 * kt + 8 * g + jj]);
                    af[jj] = f2bf_rne(v);
                    rs[mt] += v;
                }
                Afrag[mt][kt] = af;
            }
        #pragma unroll
        for (int mt = 0; mt < 4; ++mt) {
            rs[mt] += __shfl_xor(rs[mt], 16);
            rs[mt] += __shfl_xor(rs[mt], 32);
        }
        float rmax = fmaxf(fmaxf(rs[0], rs[1]), fmaxf(rs[2], rs[3]));
        #pragma unroll
        for (int o = 8; o > 0; o >>= 1) rmax = fmaxf(rmax, __shfl_xor(rmax, o));
        const float LS = __logf(rmax);

        s16x8 Bfrag[2][4];
        #pragma unroll
        for (int kt = 0; kt < 2; ++kt)
            #pragma unroll
            for (int nt = 0; nt < 4; ++nt) {
                s16x8 bf;
                #pragma unroll
                for (int jj = 0; jj < 8; ++jj)
                    bf[jj] = (32 * kt + 8 * g + jj == c + 16 * nt) ? (short)0x3F80 : (short)0;
                Bfrag[kt][nt] = bf;
            }

        float4 xr[2][4];
        #pragma unroll
        for (int p = 0; p < 2; ++p)
            #pragma unroll
            for (int tr = 0; tr < 4; ++tr)
                xr[p][tr] = *(const float4*)(xb + (size_t)(t0 + 1 + p) * N_ + 16 * tr + 4 * g);

        float c_acc = 0.f;
        #pragma unroll 2
        for (int s = 0; s < 64; ++s) {
            const int t = t0 + 1 + s;
            f32x4 Cacc[4][4];
            #pragma unroll
            for (int mt = 0; mt < 4; ++mt)
                #pragma unroll
                for (int nt = 0; nt < 4; ++nt) {
                    f32x4 z = {0.f, 0.f, 0.f, 0.f};
                    z = __builtin_amdgcn_mfma_f32_16x16x32_bf16(Afrag[mt][0], Bfrag[0][nt], z, 0, 0, 0);
                    Cacc[mt][nt] = __builtin_amdgcn_mfma_f32_16x16x32_bf16(Afrag[mt][1], Bfrag[1][nt], z, 0, 0, 0);
                }
            float4 xv[4];
            #pragma unroll
            for (int tr = 0; tr < 4; ++tr) xv[tr] = xr[s & 1][tr];
            int tpre = t + 2; if (tpre > T_ - 1) tpre = T_ - 1;
            #pragma unroll
            for (int tr = 0; tr < 4; ++tr)
                xr[s & 1][tr] = *(const float4*)(xb + (size_t)tpre * N_ + 16 * tr + 4 * g);

            const float gt = __uint_as_float(__builtin_amdgcn_readfirstlane(__float_as_uint(xv[0].x))) + LS;
            if (t < T_) {
                c_acc += gt;
                float ev[4][4];
                #pragma unroll
                for (int tr = 0; tr < 4; ++tr) {
                    ev[tr][0] = __expf(xv[tr].x - gt);
                    ev[tr][1] = __expf(xv[tr].y - gt);
                    ev[tr][2] = __expf(xv[tr].z - gt);
                    ev[tr][3] = __expf(xv[tr].w - gt);
                }
                #pragma unroll
                for (int mt = 0; mt < 4; ++mt)
                    #pragma unroll
                    for (int nt = 0; nt < 4; ++nt) {
                        s16x4 pk;
                        pk[0] = f2bf_rhu(Cacc[mt][nt][0] * ev[mt][0]);
                        pk[1] = f2bf_rhu(Cacc[mt][nt][1] * ev[mt][1]);
                        pk[2] = f2bf_rhu(Cacc[mt][nt][2] * ev[mt][2]);
                        pk[3] = f2bf_rhu(Cacc[mt][nt][3] * ev[mt][3]);
                        *(s16x4*)&myl[(16 * nt + c) * PITCH + 16 * mt + 4 * g] = pk;
                    }
                #pragma unroll
                for (int kt = 0; kt < 2; ++kt)
                    #pragma unroll
                    for (int nt = 0; nt < 4; ++nt)
                        Bfrag[kt][nt] = *(const s16x8*)&myl[(16 * nt + c) * PITCH + 32 * kt + 8 * g];
            }
        }
        // myl[j*PITCH + i] = P[i][j]; store transposed [m][n]: dst[i*64+j], coalesced
        unsigned short* dst = ws_R + (size_t)(b * 32 + k) * 4096;
        #pragma unroll
        for (int r = 0; r < 8; ++r) {
            s16x8 v = *(const s16x8*)&myl[lane * PITCH + r * 8];  // v[e] = P[8r+e][lane]
            #pragma unroll
            for (int e = 0; e < 8; ++e)
                dst[(8 * r + e) * 64 + lane] = (unsigned short)v[e];
        }
        if (lane == 0) ws_c[b * 32 + k] = c_acc;
    }
}

// Kernel 2: per-batch combine, R rows [m][n] -> b128 loads + next-chunk prefetch.
__global__ __launch_bounds__(64) void asg_k2(
    const float* __restrict__ x,
    const float* __restrict__ ws_c,
    const unsigned short* __restrict__ ws_R,
    const float* __restrict__ ws_fac,
    float* __restrict__ out)
{
    __shared__ __align__(16) float sa[N_];
    const int b = blockIdx.x, lane = threadIdx.x;
    float a0 = x[(size_t)b * T_ * N_ + lane];
    float m0 = a0;
    #pragma unroll
    for (int o = 32; o > 0; o >>= 1) m0 = fmaxf(m0, __shfl_xor(m0, o));
    float  a  = __expf(a0 - m0);
    double Cd = (double)m0;

    const unsigned short* Rb = ws_R + (size_t)b * 32 * 4096 + lane * 64;
    s16x8 cur[8], nxt[8];
    #pragma unroll
    for (int r = 0; r < 8; ++r) cur[r] = ((const s16x8*)Rb)[r];

    for (int kk = 0; kk < 32; ++kk) {
        const int kn = (kk < 31) ? kk + 1 : 31;
        #pragma unroll
        for (int r = 0; r < 8; ++r) nxt[r] = ((const s16x8*)(Rb + (size_t)kn * 4096))[r];

        sa[lane] = a;
        __syncthreads();
        float4 sav[16];
        #pragma unroll
        for (int q = 0; q < 16; ++q) sav[q] = ((const float4*)sa)[q];
        __syncthreads();

        float acc4[4] = {0.f, 0.f, 0.f, 0.f};
        #pragma unroll
        for (int r = 0; r < 8; ++r) {
            const float4 s0 = sav[2 * r], s1 = sav[2 * r + 1];
            acc4[0] = fmaf(bf2f((unsigned short)cur[r][0]), s0.x, acc4[0]);
            acc4[1] = fmaf(bf2f((unsigned short)cur[r][1]), s0.y, acc4[1]);
            acc4[2] = fmaf(bf2f((unsigned short)cur[r][2]), s0.z, acc4[2]);
            acc4[3] = fmaf(bf2f((unsigned short)cur[r][3]), s0.w, acc4[3]);
            acc4[0] = fmaf(bf2f((unsigned short)cur[r][4]), s1.x, acc4[0]);
            acc4[1] = fmaf(bf2f((unsigned short)cur[r][5]), s1.y, acc4[1]);
            acc4[2] = fmaf(bf2f((unsigned short)cur[r][6]), s1.z, acc4[2]);
            acc4[3] = fmaf(bf2f((unsigned short)cur[r][7]), s1.w, acc4[3]);
        }
        float acc = (acc4[0] + acc4[1]) + (acc4[2] + acc4[3]);
        float rm = acc;
        #pragma unroll
        for (int o = 32; o > 0; o >>= 1) rm = fmaxf(rm, __shfl_xor(rm, o));
        a = acc / rm;
        Cd += (double)(__logf(rm) + ws_c[b * 32 + kk]);
        #pragma unroll
        for (int r = 0; r < 8; ++r) cur[r] = nxt[r];
    }
    float ssum = a;
    #pragma unroll
    for (int o = 32; o > 0; o >>= 1) ssum += __shfl_xor(ssum, o);
    if (lane == 0) {
        float fcc = (float)(Cd + (double)__logf(ssum));
        out[b] = fcc - ws_fac[b];
    }
}

extern "C" void kernel_launch(void* const* d_in, const int* in_sizes, int n_in,
                              void* d_out, int out_size, void* d_ws, size_t ws_size,
                              hipStream_t stream) {
    (void)in_sizes; (void)n_in; (void)out_size; (void)ws_size;
    const float* xin    = (const float*)d_in[0];
    const int*   target = (const int*)  d_in[1];
    const int*   tsz    = (const int*)  d_in[2];
    const float* trans  = (const float*)d_in[3];
    float* out = (float*)d_out;

    float*          ws_c   = (float*)d_ws;                                   // 16 KB
    unsigned short* ws_R   = (unsigned short*)((char*)d_ws + 16384);         // 33.55 MB
    float*          ws_fac = (float*)((char*)d_ws + 16384 + (size_t)B_ * 32 * 4096 * 2);

    asg_k1<<<dim3(1056), dim3(256), 0, stream>>>(xin, target, tsz, trans, ws_c, ws_R, ws_fac);
    asg_k2<<<dim3(B_), dim3(64), 0, stream>>>(xin, ws_c, ws_R, ws_fac, out);
}

// Round 5
// 315.244 us; speedup vs baseline: 3.8770x; 1.2491x over previous
//
#include <hip/hip_runtime.h>

#define B_ 128
#define T_ 2048
#define N_ 64
#define L_ 256
#define NEGV (-1e30f)
#define PITCH 72   // shorts per LDS row (64 + 8 pad), 144 B -> keeps b128 16B-aligned
#define LOG2E 1.4426950408889634f
#define LN2   0.6931471805599453f

typedef short  s16x4 __attribute__((ext_vector_type(4)));
typedef short  s16x8 __attribute__((ext_vector_type(8)));
typedef float  f32x4 __attribute__((ext_vector_type(4)));
typedef unsigned int u32x2 __attribute__((ext_vector_type(2)));

__device__ __forceinline__ short f2bf_rne(float f) {
    unsigned u = __float_as_uint(f);
    unsigned r = (u + 0x7FFFu + ((u >> 16) & 1u)) >> 16;
    return (short)r;
}
__device__ __forceinline__ float bf2f(unsigned short u) {
    return __uint_as_float(((unsigned)u) << 16);
}
// pack 2 floats -> 2 bf16 (round-half-up) in one u32 via v_perm_b32
__device__ __forceinline__ unsigned pkpair(float lo, float hi) {
    return __builtin_amdgcn_perm(__float_as_uint(hi) + 0x8000u,
                                 __float_as_uint(lo) + 0x8000u, 0x07060302u);
}
__device__ __forceinline__ float bperm(int byteaddr, float v) {
    return __int_as_float(__builtin_amdgcn_ds_bpermute(byteaddr, __float_as_int(v)));
}
// logaddexp in log2 domain (v_exp_f32/v_log_f32 are base-2)
__device__ __forceinline__ float lse2b(float p, float q) {
    float mx = fmaxf(p, q);
    float t  = __builtin_amdgcn_exp2f(-fabsf(p - q));
    return mx + __builtin_amdgcn_logf(1.f + t);
}

// Kernel 1: waves 0..127 fwd-fac, 128..255 bwd-fac, rest fcc chunk builders.
__global__ __launch_bounds__(256, 2) void asg_k1(
    const float* __restrict__ x,       // (B,T,N)
    const int*   __restrict__ target,  // (B,L)
    const int*   __restrict__ tsize,   // (B,)
    const float* __restrict__ trans,   // (N,N)
    float* __restrict__ ws_c,          // (B,32) chunk log-scales
    unsigned short* __restrict__ ws_R, // (B,32,64,64) bf16 chunk matrices [m][n]
    float* __restrict__ ws_v,          // (B,256) alpha_1023 (log2 domain)
    float* __restrict__ ws_w)          // (B,256) beta_1023  (log2 domain)
{
    __shared__ short lds[4][N_ * PITCH];
    const int wid  = threadIdx.x >> 6;
    const int lane = threadIdx.x & 63;
    const int W    = blockIdx.x * 4 + wid;

    if (W < 128) {
        // ---------------- FAC forward: alpha_0 .. alpha_1023 ----------------
        const int b  = W;
        const float* __restrict__ xb = x + (size_t)b * T_ * N_;
        const int l0 = lane * 4;
        int tga[4]; float slf[4], mv[4], a[4];
        #pragma unroll
        for (int j = 0; j < 4; ++j) {
            const int tv = target[b * L_ + l0 + j];
            tga[j] = tv << 2;
            slf[j] = trans[tv * N_ + tv] * LOG2E;
            if (j > 0) mv[j] = trans[tv * N_ + (target[b * L_ + l0 + j - 1])] * LOG2E;
            a[j] = NEGV;
        }
        const int tR  = target[b * L_ + ((l0 - 1 >= 0) ? l0 - 1 : 0)];
        const int tR1 = target[b * L_ + ((l0 - 2 >= 0) ? l0 - 2 : 0)];
        const int tgR = tR << 2;
        const float slfR = trans[tR * N_ + tR] * LOG2E;
        const float mvR  = trans[tR * N_ + tR1] * LOG2E;
        mv[0] = trans[(tga[0] >> 2) * N_ + tR] * LOG2E;
        if (lane == 0) a[0] = xb[tga[0] >> 2] * LOG2E;   // alpha0[0]
        float red = NEGV;
        const int upA = ((lane == 0) ? 0 : lane - 1) << 2;

        float xr[16];
        #pragma unroll
        for (int i = 0; i < 16; ++i) xr[i] = xb[(size_t)(1 + i) * N_ + lane];
        float sc = xr[0] * LOG2E;
        float eR = bperm(tgR, sc);
        float e0 = bperm(tga[0], sc), e1 = bperm(tga[1], sc),
              e2 = bperm(tga[2], sc), e3 = bperm(tga[3], sc);
        float bp = bperm(upA, a[2]);

        #define FWD_STEP(i, rp, RF)                                             \
        {                                                                       \
            const float ceR = eR, c0 = e0, c1 = e1, c2 = e2, c3 = e3;           \
            float scn = xr[((i) + 1) & 15] * LOG2E;                             \
            eR = bperm(tgR, scn);                                               \
            e0 = bperm(tga[0], scn); e1 = bperm(tga[1], scn);                   \
            e2 = bperm(tga[2], scn); e3 = bperm(tga[3], scn);                   \
            if (RF) xr[i] = (rp)[lane];                                         \
            const float n0 = lse2b(a[0] + slf[0], red  + mv[0]) + c0;           \
            const float n1 = lse2b(a[1] + slf[1], a[0] + mv[1]) + c1;           \
            const float n2 = lse2b(a[2] + slf[2], a[1] + mv[2]) + c2;           \
            const float n3 = lse2b(a[3] + slf[3], a[2] + mv[3]) + c3;           \
            const float nr = lse2b(red + slfR,    bp   + mvR)   + ceR;          \
            bp = bperm(upA, n2);                                                \
            a[0] = n0; a[1] = n1; a[2] = n2; a[3] = n3;                         \
            red = (lane == 0) ? NEGV : nr;                                      \
        }
        for (int u = 0; u < 63; ++u) {                  // t = 1..1008
            const float* __restrict__ xp = xb + (size_t)(16 * u + 17) * N_;
            #pragma unroll
            for (int i = 0; i < 16; ++i) FWD_STEP(i, xp + i * N_, true);
        }
        #pragma unroll
        for (int i = 0; i < 15; ++i) FWD_STEP(i, xb, false);   // t = 1009..1023
        #undef FWD_STEP
        *(float4*)(ws_v + b * 256 + l0) = make_float4(a[0], a[1], a[2], a[3]);
    } else if (W < 256) {
        // ---------------- FAC backward: beta_2047 .. beta_1023 ----------------
        const int b  = W - 128;
        const float* __restrict__ xb = x + (size_t)b * T_ * N_;
        const int l0 = lane * 4;
        const int lt = tsize[b] - 1;
        int tga[4]; float slf[4], mvin[4], a[4];
        #pragma unroll
        for (int j = 0; j < 4; ++j) {
            const int tv = target[b * L_ + l0 + j];
            tga[j] = tv << 2;
            slf[j] = trans[tv * N_ + tv] * LOG2E;
            if (j > 0) mvin[j] = trans[tv * N_ + (target[b * L_ + l0 + j - 1])] * LOG2E;
            a[j] = (l0 + j == lt) ? 0.f : NEGV;
        }
        const int tR  = target[b * L_ + ((l0 + 4 <= L_ - 1) ? l0 + 4 : L_ - 1)];
        const int tR2 = target[b * L_ + ((l0 + 5 <= L_ - 1) ? l0 + 5 : L_ - 1)];
        const int tgR = tR << 2, tgR2 = tR2 << 2;
        const float slfR = trans[tR * N_ + tR] * LOG2E;
        const float mvR  = trans[tR * N_ + (tga[3] >> 2)] * LOG2E;  // move into 4m+4
        const float mvR2 = trans[tR2 * N_ + tR] * LOG2E;            // move into 4m+5
        float red = (l0 + 4 == lt) ? 0.f : NEGV;
        const int dnA = ((lane == 63) ? 63 : lane + 1) << 2;

        float xr[16];
        #pragma unroll
        for (int i = 0; i < 16; ++i) xr[i] = xb[(size_t)(2047 - i) * N_ + lane];
        float sc = xr[0] * LOG2E;
        float eR = bperm(tgR, sc), eR2 = bperm(tgR2, sc);
        float e0 = bperm(tga[0], sc), e1 = bperm(tga[1], sc),
              e2 = bperm(tga[2], sc), e3 = bperm(tga[3], sc);
        float bp = bperm(dnA, a[1]);

        #define BWD_STEP(i, rp, RF)                                             \
        {                                                                       \
            const float ceR = eR, ceR2 = eR2, c0 = e0, c1 = e1, c2 = e2, c3 = e3;\
            float scn = xr[((i) + 1) & 15] * LOG2E;                             \
            eR = bperm(tgR, scn); eR2 = bperm(tgR2, scn);                       \
            e0 = bperm(tga[0], scn); e1 = bperm(tga[1], scn);                   \
            e2 = bperm(tga[2], scn); e3 = bperm(tga[3], scn);                   \
            if (RF) xr[i] = (rp)[lane];                                         \
            const float t0 = a[0] + c0, t1 = a[1] + c1, t2 = a[2] + c2,         \
                        t3 = a[3] + c3, tr = red + ceR;                         \
            const float n0 = lse2b(t0 + slf[0], t1 + mvin[1]);                  \
            const float n1 = lse2b(t1 + slf[1], t2 + mvin[2]);                  \
            const float n2 = lse2b(t2 + slf[2], t3 + mvin[3]);                  \
            const float n3 = lse2b(t3 + slf[3], tr + mvR);                      \
            const float nr = lse2b(tr + slfR, bp + ceR2 + mvR2);                \
            bp = bperm(dnA, n1);                                                \
            a[0] = n0; a[1] = n1; a[2] = n2; a[3] = n3;                         \
            red = (lane == 63) ? NEGV : nr;                                     \
        }
        for (int u = 0; u < 63; ++u) {                  // t = 2047..1040
            const float* __restrict__ xp = xb + (size_t)(2047 - 16 * u - 16) * N_;
            #pragma unroll
            for (int i = 0; i < 16; ++i) BWD_STEP(i, xp - (size_t)i * N_, true);
        }
        #pragma unroll
        for (int i = 0; i < 16; ++i) BWD_STEP(i, xb, false);   // t = 1039..1024
        #undef BWD_STEP
        *(float4*)(ws_w + b * 256 + l0) = make_float4(a[0], a[1], a[2], a[3]);
    } else {
        // ---------------- FCC chunk: P = prod_s D_t*Ehat over 64 steps --------
        const int task = W - 256;
        const int b = task >> 5, k = task & 31;
        const int c = lane & 15, g = lane >> 4;
        const float* __restrict__ xb = x + (size_t)b * T_ * N_;
        const int t0 = k * 64;
        short* __restrict__ myl = lds[wid];

        s16x8 Afrag[4][2];
        float rs[4] = {0.f, 0.f, 0.f, 0.f};
        #pragma unroll
        for (int mt = 0; mt < 4; ++mt)
            #pragma unroll
            for (int kt = 0; kt < 2; ++kt) {
                s16x8 af;
                #pragma unroll
                for (int jj = 0; jj < 8; ++jj) {
                    float v = __expf(trans[(c + 16 * mt) * N_ + 32 * kt + 8 * g + jj]);
                    af[jj] = f2bf_rne(v);
                    rs[mt] += v;
                }
                Afrag[mt][kt] = af;
            }
        #pragma unroll
        for (int mt = 0; mt < 4; ++mt) {
            rs[mt] += __shfl_xor(rs[mt], 16);
            rs[mt] += __shfl_xor(rs[mt], 32);
        }
        float rmax = fmaxf(fmaxf(rs[0], rs[1]), fmaxf(rs[2], rs[3]));
        #pragma unroll
        for (int o = 8; o > 0; o >>= 1) rmax = fmaxf(rmax, __shfl_xor(rmax, o));
        const float LS = __logf(rmax);

        s16x8 Bfrag[2][4];
        #pragma unroll
        for (int kt = 0; kt < 2; ++kt)
            #pragma unroll
            for (int nt = 0; nt < 4; ++nt) {
                s16x8 bf;
                #pragma unroll
                for (int jj = 0; jj < 8; ++jj)
                    bf[jj] = (32 * kt + 8 * g + jj == c + 16 * nt) ? (short)0x3F80 : (short)0;
                Bfrag[kt][nt] = bf;
            }

        float4 xr[2][4];
        #pragma unroll
        for (int p = 0; p < 2; ++p)
            #pragma unroll
            for (int tr = 0; tr < 4; ++tr)
                xr[p][tr] = *(const float4*)(xb + (size_t)(t0 + 1 + p) * N_ + 16 * tr + 4 * g);

        float c_acc = 0.f;
        #pragma unroll 2
        for (int s = 0; s < 64; ++s) {
            const int t = t0 + 1 + s;
            f32x4 Cacc[4][4];
            #pragma unroll
            for (int mt = 0; mt < 4; ++mt)
                #pragma unroll
                for (int nt = 0; nt < 4; ++nt) {
                    f32x4 z = {0.f, 0.f, 0.f, 0.f};
                    z = __builtin_amdgcn_mfma_f32_16x16x32_bf16(Afrag[mt][0], Bfrag[0][nt], z, 0, 0, 0);
                    Cacc[mt][nt] = __builtin_amdgcn_mfma_f32_16x16x32_bf16(Afrag[mt][1], Bfrag[1][nt], z, 0, 0, 0);
                }
            float4 xv[4];
            #pragma unroll
            for (int tr = 0; tr < 4; ++tr) xv[tr] = xr[s & 1][tr];
            int tpre = t + 2; if (tpre > T_ - 1) tpre = T_ - 1;
            #pragma unroll
            for (int tr = 0; tr < 4; ++tr)
                xr[s & 1][tr] = *(const float4*)(xb + (size_t)tpre * N_ + 16 * tr + 4 * g);

            const float gt = __uint_as_float(__builtin_amdgcn_readfirstlane(__float_as_uint(xv[0].x))) + LS;
            if (t < T_) {
                c_acc += gt;
                float ev[4][4];
                #pragma unroll
                for (int tr = 0; tr < 4; ++tr) {
                    ev[tr][0] = __expf(xv[tr].x - gt);
                    ev[tr][1] = __expf(xv[tr].y - gt);
                    ev[tr][2] = __expf(xv[tr].z - gt);
                    ev[tr][3] = __expf(xv[tr].w - gt);
                }
                #pragma unroll
                for (int mt = 0; mt < 4; ++mt)
                    #pragma unroll
                    for (int nt = 0; nt < 4; ++nt) {
                        u32x2 pk;
                        pk[0] = pkpair(Cacc[mt][nt][0] * ev[mt][0], Cacc[mt][nt][1] * ev[mt][1]);
                        pk[1] = pkpair(Cacc[mt][nt][2] * ev[mt][2], Cacc[mt][nt][3] * ev[mt][3]);
                        *(u32x2*)&myl[(16 * nt + c) * PITCH + 16 * mt + 4 * g] = pk;
                    }
                #pragma unroll
                for (int kt = 0; kt < 2; ++kt)
                    #pragma unroll
                    for (int nt = 0; nt < 4; ++nt)
                        Bfrag[kt][nt] = *(const s16x8*)&myl[(16 * nt + c) * PITCH + 32 * kt + 8 * g];
            }
        }
        unsigned short* dst = ws_R + (size_t)(b * 32 + k) * 4096;
        #pragma unroll
        for (int r = 0; r < 8; ++r) {
            s16x8 v = *(const s16x8*)&myl[lane * PITCH + r * 8];  // v[e] = P[8r+e][lane]
            #pragma unroll
            for (int e = 0; e < 8; ++e)
                dst[(8 * r + e) * 64 + lane] = (unsigned short)v[e];
        }
        if (lane == 0) ws_c[b * 32 + k] = c_acc;
    }
}

// Kernel 2: wave0 = fcc chunk combine (LDS-staged, double-buffered);
//           wave1 = fwd/bwd fac combine. One block per batch.
__global__ __launch_bounds__(128) void asg_k2(
    const float* __restrict__ x,
    const float* __restrict__ ws_c,
    const unsigned short* __restrict__ ws_R,
    const float* __restrict__ ws_v,
    const float* __restrict__ ws_w,
    float* __restrict__ out)
{
    __shared__ short rb[2][N_ * PITCH];
    __shared__ __align__(16) float sa[N_];
    __shared__ float sres[2];
    const int b = blockIdx.x, tid = threadIdx.x, lane = tid & 63;

    if (tid < 64) {
        float a0 = x[(size_t)b * T_ * N_ + lane];
        float m0 = a0;
        #pragma unroll
        for (int o = 32; o > 0; o >>= 1) m0 = fmaxf(m0, __shfl_xor(m0, o));
        float  a  = __expf(a0 - m0);
        double Cd = (double)m0;

        const unsigned short* Rb = ws_R + (size_t)b * 32 * 4096;
        const int frow = (lane >> 3), fcol = (lane & 7) * 8;  // staging lane slot
        // preload chunk 0 -> buf 0 (coalesced b128)
        {
            #pragma unroll
            for (int q = 0; q < 8; ++q) {
                s16x8 v = *(const s16x8*)(Rb + lane * 8 + 512 * q);
                *(s16x8*)&rb[0][(frow + 8 * q) * PITCH + fcol] = v;
            }
        }
        for (int kk = 0; kk < 32; ++kk) {
            const int kn = (kk < 31) ? kk + 1 : 31;
            s16x8 nv[8];
            #pragma unroll
            for (int q = 0; q < 8; ++q)
                nv[q] = *(const s16x8*)(Rb + (size_t)kn * 4096 + lane * 8 + 512 * q);

            sa[lane] = a;
            float4 sav[16];
            #pragma unroll
            for (int q = 0; q < 16; ++q) sav[q] = ((const float4*)sa)[q];

            float acc4[4] = {0.f, 0.f, 0.f, 0.f};
            #pragma unroll
            for (int u = 0; u < 8; ++u) {
                s16x8 rr = *(const s16x8*)&rb[kk & 1][lane * PITCH + u * 8];
                const float4 s0 = sav[2 * u], s1 = sav[2 * u + 1];
                acc4[0] = fmaf(bf2f((unsigned short)rr[0]), s0.x, acc4[0]);
                acc4[1] = fmaf(bf2f((unsigned short)rr[1]), s0.y, acc4[1]);
                acc4[2] = fmaf(bf2f((unsigned short)rr[2]), s0.z, acc4[2]);
                acc4[3] = fmaf(bf2f((unsigned short)rr[3]), s0.w, acc4[3]);
                acc4[0] = fmaf(bf2f((unsigned short)rr[4]), s1.x, acc4[0]);
                acc4[1] = fmaf(bf2f((unsigned short)rr[5]), s1.y, acc4[1]);
                acc4[2] = fmaf(bf2f((unsigned short)rr[6]), s1.z, acc4[2]);
                acc4[3] = fmaf(bf2f((unsigned short)rr[7]), s1.w, acc4[3]);
            }
            float acc = (acc4[0] + acc4[1]) + (acc4[2] + acc4[3]);
            float rm = acc;
            #pragma unroll
            for (int o = 32; o > 0; o >>= 1) rm = fmaxf(rm, __shfl_xor(rm, o));
            a = acc / rm;
            Cd += (double)(__logf(rm) + ws_c[b * 32 + kk]);

            #pragma unroll
            for (int q = 0; q < 8; ++q)
                *(s16x8*)&rb[(kk + 1) & 1][(frow + 8 * q) * PITCH + fcol] = nv[q];
        }
        float ssum = a;
        #pragma unroll
        for (int o = 32; o > 0; o >>= 1) ssum += __shfl_xor(ssum, o);
        if (lane == 0) sres[0] = (float)(Cd + (double)__logf(ssum));
    } else {
        // fac combine: F = ln-domain lse over 256 cells of (alpha+beta), log2 inputs
        float4 v4 = ((const float4*)(ws_v + b * 256))[lane];
        float4 w4 = ((const float4*)(ws_w + b * 256))[lane];
        const float s0 = v4.x + w4.x, s1 = v4.y + w4.y,
                    s2 = v4.z + w4.z, s3 = v4.w + w4.w;
        float m = fmaxf(fmaxf(s0, s1), fmaxf(s2, s3));
        #pragma unroll
        for (int o = 32; o > 0; o >>= 1) m = fmaxf(m, __shfl_xor(m, o));
        float sum = __builtin_amdgcn_exp2f(s0 - m) + __builtin_amdgcn_exp2f(s1 - m)
                  + __builtin_amdgcn_exp2f(s2 - m) + __builtin_amdgcn_exp2f(s3 - m);
        #pragma unroll
        for (int o = 32; o > 0; o >>= 1) sum += __shfl_xor(sum, o);
        if (lane == 0) sres[1] = (m + __builtin_amdgcn_logf(sum)) * LN2;
    }
    __syncthreads();
    if (tid == 0) out[b] = sres[0] - sres[1];
}

extern "C" void kernel_launch(void* const* d_in, const int* in_sizes, int n_in,
                              void* d_out, int out_size, void* d_ws, size_t ws_size,
                              hipStream_t stream) {
    (void)in_sizes; (void)n_in; (void)out_size; (void)ws_size;
    const float* xin    = (const float*)d_in[0];
    const int*   target = (const int*)  d_in[1];
    const int*   tsz    = (const int*)  d_in[2];
    const float* trans  = (const float*)d_in[3];
    float* out = (float*)d_out;

    float*          ws_c = (float*)d_ws;                                    // 16 KB
    unsigned short* ws_R = (unsigned short*)((char*)d_ws + 16384);          // 33.55 MB
    float*          ws_v = (float*)((char*)d_ws + 16384 + 33554432);        // 128 KB
    float*          ws_w = (float*)((char*)d_ws + 16384 + 33554432 + 131072);

    // 64 fac blocks (128 fwd + 128 bwd waves) + 1024 chunk blocks
    asg_k1<<<dim3(1088), dim3(256), 0, stream>>>(xin, target, tsz, trans,
                                                 ws_c, ws_R, ws_v, ws_w);
    asg_k2<<<dim3(B_), dim3(128), 0, stream>>>(xin, ws_c, ws_R, ws_v, ws_w, out);
}